// Round 3
// baseline (689.383 us; speedup 1.0000x reference)
//
#include <hip/hip_runtime.h>
#include <math.h>

// VariableSelectionNetwork — round 2: m97-style K-loop for the var-GRN kernel.
// B staged via global_load_lds(16B) double-buffered (one stream per block, not
// per wave -> kills the L2 hot-spot that capped round 1 at MfmaUtil 11.7%).
// X2 kept packed-bf16 in regs for the gate; X2->LDS transform via lane-pair
// shuffle + v_perm so stores are aligned b32 (round 1: scalar u16, 19.9M confl).
// LDS: sA 64KB (A1/X2, XOR-swizzled) + sB 2x32KB = 128KB -> 1 block/CU.

#define H 512
#define NF 4
#define MTOT 32768

typedef unsigned short u16;
typedef unsigned int u32;
typedef __attribute__((ext_vector_type(8))) short short8;   // 8 bf16 = 4 VGPRs
typedef __attribute__((ext_vector_type(4))) float f32x4;    // MFMA C/D

__device__ __forceinline__ u16 f2bf(float x) {
  union { float f; u32 u; } v; v.f = x;
  return (u16)((v.u + 0x7fffu + ((v.u >> 16) & 1u)) >> 16);  // RNE
}
__device__ __forceinline__ float bf2f(u32 h16) {
  union { u32 u; float f; } v; v.u = h16 << 16;
  return v.f;
}
__device__ __forceinline__ float elu_f(float x) { return x > 0.0f ? x : expm1f(x); }
__device__ __forceinline__ float sigmoid_f(float x) { return 1.0f / (1.0f + expf(-x)); }

// async global->LDS, 16B per lane. LDS dest must be wave-uniform base + lane*16.
__device__ __forceinline__ void glld16(const void* g, void* l) {
  __builtin_amdgcn_global_load_lds(
      (const __attribute__((address_space(1))) u32*)(unsigned long long)(uintptr_t)g,
      (__attribute__((address_space(3))) u32*)(u32)(uintptr_t)l, 16, 0, 0);
}

#define MFMA16(a, b, c) __builtin_amdgcn_mfma_f32_16x16x32_bf16((a), (b), (c), 0, 0, 0)

// ---------------- pack_weights: fp32 -> bf16 B-fragment-major ----------------
// Packed index: ((((f*16 + kk)*32 + nt)*64 + lane)*8 + j). One kk-chunk
// (32 k x 512 n) = 16384 u16 = 32KB, contiguous -> linear glld staging.
__global__ __launch_bounds__(256)
void pack_weights(const float* __restrict__ W2, const float* __restrict__ Wg,
                  u16* __restrict__ W2p, u16* __restrict__ Wgp) {
  int t = blockIdx.x * 256 + threadIdx.x;   // 0 .. 262143
  int lane = t & 63;  int rest = t >> 6;
  int nt = rest & 31; rest >>= 5;
  int kk = rest & 15; rest >>= 4;
  int f  = rest & 3;  rest >>= 2;
  int mat = rest;                           // 0 = W2, 1 = Wg
  const float* W = (mat ? Wg : W2) + (size_t)f * H * H;
  u16* P = (mat ? Wgp : W2p) + ((((size_t)f * 16 + kk) * 32 + nt) * 64 + lane) * 8;
  int n  = nt * 16 + (lane & 15);
  int k0 = kk * 32 + (lane >> 4) * 8;
  short8 pk;
  #pragma unroll
  for (int j = 0; j < 8; ++j) pk[j] = (short)f2bf(W[(size_t)(k0 + j) * H + n]);
  *(short8*)P = pk;
}

// ---------------- Kernel A: context GRN + softmax selection ----------------
__global__ __launch_bounds__(512)
void ctx_grn_kernel(const float* __restrict__ in,
                    const float* __restrict__ W1c, const float* __restrict__ b1c,
                    const float* __restrict__ W2c, const float* __restrict__ b2c,
                    const float* __restrict__ Wgc, const float* __restrict__ bgc,
                    const float* __restrict__ gamma_c, const float* __restrict__ beta_c,
                    const float* __restrict__ Wsel, const float* __restrict__ bsel,
                    float* __restrict__ sel_ws,      // [B, F]
                    float* __restrict__ selw_out)    // [B, T, 1, F] flat
{
  __shared__ float sFlat[H];
  __shared__ float sX[H];
  __shared__ float sX2[H];
  __shared__ float sPartS[8], sPartQ[8];
  __shared__ float sLog[8][NF];
  __shared__ float sSel[NF];

  const int b = blockIdx.x;
  const int tid = threadIdx.x;

  sFlat[tid] = in[b * H + tid];
  __syncthreads();

  float acc = b1c[tid];
  #pragma unroll 8
  for (int d = 0; d < H; ++d) acc = fmaf(sFlat[d], W1c[d * H + tid], acc);
  sX[tid] = elu_f(acc);
  __syncthreads();

  acc = b2c[tid];
  #pragma unroll 8
  for (int d = 0; d < H; ++d) acc = fmaf(sX[d], W2c[d * H + tid], acc);
  sX2[tid] = acc;
  __syncthreads();

  acc = bgc[tid];
  #pragma unroll 8
  for (int d = 0; d < H; ++d) acc = fmaf(sX2[d], Wgc[d * H + tid], acc);
  const float g = sigmoid_f(acc);
  const float y = g * sX2[tid] + (1.0f - g) * sFlat[tid];

  float s = y, q = y * y;
  #pragma unroll
  for (int m = 32; m >= 1; m >>= 1) { s += __shfl_xor(s, m, 64); q += __shfl_xor(q, m, 64); }
  const int wid = tid >> 6;
  if ((tid & 63) == 0) { sPartS[wid] = s; sPartQ[wid] = q; }
  __syncthreads();
  s = 0.0f; q = 0.0f;
  #pragma unroll
  for (int w = 0; w < 8; ++w) { s += sPartS[w]; q += sPartQ[w]; }
  const float mean = s * (1.0f / H);
  const float var  = q * (1.0f / H) - mean * mean;
  const float rstd = rsqrtf(var + 1e-3f);
  const float ctx  = gamma_c[tid] * ((y - mean) * rstd) + beta_c[tid];

  float p0 = ctx * Wsel[tid * NF + 0];
  float p1 = ctx * Wsel[tid * NF + 1];
  float p2 = ctx * Wsel[tid * NF + 2];
  float p3 = ctx * Wsel[tid * NF + 3];
  #pragma unroll
  for (int m = 32; m >= 1; m >>= 1) {
    p0 += __shfl_xor(p0, m, 64); p1 += __shfl_xor(p1, m, 64);
    p2 += __shfl_xor(p2, m, 64); p3 += __shfl_xor(p3, m, 64);
  }
  if ((tid & 63) == 0) { sLog[wid][0] = p0; sLog[wid][1] = p1; sLog[wid][2] = p2; sLog[wid][3] = p3; }
  __syncthreads();
  if (tid == 0) {
    float z[NF];
    for (int f = 0; f < NF; ++f) {
      float t = bsel[f];
      for (int w = 0; w < 8; ++w) t += sLog[w][f];
      z[f] = t;
    }
    float mx = fmaxf(fmaxf(z[0], z[1]), fmaxf(z[2], z[3]));
    float e[NF]; float se = 0.0f;
    for (int f = 0; f < NF; ++f) { e[f] = expf(z[f] - mx); se += e[f]; }
    float inv = 1.0f / se;
    for (int f = 0; f < NF; ++f) sSel[f] = e[f] * inv;
  }
  __syncthreads();
  if (tid < NF) sel_ws[b * NF + tid] = sSel[tid];
  selw_out[b * H + tid] = sSel[tid & 3];
}

// ---------------- Kernel B: MFMA var-GRNs, LDS-staged B ----------------
// 512 thr = 8 waves, M-tile 64, wave n-slice 64 (4 nt), 4 mt -> 4x4 frags.
__global__ __launch_bounds__(512, 2)
void vsn_mfma(const float* __restrict__ in,     // [MTOT, F]
              const float* __restrict__ w1, const float* __restrict__ b1,
              const float* __restrict__ b2, const float* __restrict__ bg,
              const float* __restrict__ gamma, const float* __restrict__ beta,
              const u16* __restrict__ W2p, const u16* __restrict__ Wgp,
              const float* __restrict__ sel_ws,  // [B, F]
              float* __restrict__ out)           // [MTOT, H]
{
  __shared__ __align__(16) u16 smem[65536];      // 128 KB total
  u16* const sA  = smem;                         // 64 KB: [m][k] swizzled bf16
  u16* const sB0 = smem + 32768;                 // 32 KB: B chunk buf 0
  u16* const sB1 = smem + 49152;                 // 32 KB: B chunk buf 1
  float* const sRed = (float*)smem;              // 4 KB overlay on sA (post-GEMM2)

  const int tid  = threadIdx.x;
  const int wid  = tid >> 6;
  const int lane = tid & 63;
  const int quad = lane >> 4;
  const int col  = lane & 15;
  const bool even = (lane & 1) == 0;
  const int row0 = blockIdx.x * 64;
  const int bidx = row0 >> 7;

  f32x4 outacc[4][4];
  #pragma unroll
  for (int mt = 0; mt < 4; ++mt)
    #pragma unroll
    for (int nt = 0; nt < 4; ++nt) outacc[mt][nt] = (f32x4){0.f, 0.f, 0.f, 0.f};

  for (int f = 0; f < NF; ++f) {
    const u16* W2f = W2p + (size_t)f * 16 * 16384;
    const u16* Wgf = Wgp + (size_t)f * 16 * 16384;

    // stage GEMM1 chunk0 -> sB0 (latency overlapped by A1 phase below)
    {
      const u16* src = W2f + tid * 8;
      #pragma unroll
      for (int j = 0; j < 4; ++j) glld16(src + j * 4096, sB0 + tid * 8 + j * 4096);
    }
    // ---------- A1 phase: sA[m][k] = bf16(elu(v[m]*w1[k] + b1[k])) ----------
    {
      const int m  = tid >> 3;
      const int k0 = (tid & 7) * 64;
      const float v = in[(row0 + m) * NF + f];
      const float* w1f = w1 + f * H;
      const float* b1f = b1 + f * H;
      #pragma unroll
      for (int gg = 0; gg < 8; ++gg) {
        const int k = k0 + gg * 8;
        short8 pk;
        #pragma unroll
        for (int j = 0; j < 8; ++j)
          pk[j] = (short)f2bf(elu_f(fmaf(v, w1f[k + j], b1f[k + j])));
        const int grp = (k >> 3) ^ (m & 7);
        *(short8*)&sA[m * 512 + grp * 8] = pk;
      }
    }
    __syncthreads();   // drains glld chunk0 + A1 writes

    f32x4 acc[4][4];
    #pragma unroll
    for (int mt = 0; mt < 4; ++mt)
      #pragma unroll
      for (int nt = 0; nt < 4; ++nt) acc[mt][nt] = (f32x4){0.f, 0.f, 0.f, 0.f};

    // ================= GEMM1: X2 = A1 @ W2f =================
    #pragma unroll 1
    for (int kk = 0; kk < 16; ++kk) {
      if (kk < 15) {   // stage chunk kk+1 into the other buffer
        const u16* src = W2f + (kk + 1) * 16384 + tid * 8;
        u16* dst = (((kk + 1) & 1) ? sB1 : sB0) + tid * 8;
        #pragma unroll
        for (int j = 0; j < 4; ++j) glld16(src + j * 4096, dst + j * 4096);
      }
      const u16* bp = ((kk & 1) ? sB1 : sB0) + wid * 2048 + lane * 8;
      short8 bb0 = *(const short8*)(bp);
      short8 bb1 = *(const short8*)(bp + 512);
      short8 bb2 = *(const short8*)(bp + 1024);
      short8 bb3 = *(const short8*)(bp + 1536);
      const int g = (kk * 4 + quad) ^ (col & 7);
      short8 a0 = *(const short8*)&sA[(     col) * 512 + g * 8];
      short8 a1 = *(const short8*)&sA[(16 + col) * 512 + g * 8];
      short8 a2 = *(const short8*)&sA[(32 + col) * 512 + g * 8];
      short8 a3 = *(const short8*)&sA[(48 + col) * 512 + g * 8];
      acc[0][0] = MFMA16(a0, bb0, acc[0][0]); acc[0][1] = MFMA16(a0, bb1, acc[0][1]);
      acc[0][2] = MFMA16(a0, bb2, acc[0][2]); acc[0][3] = MFMA16(a0, bb3, acc[0][3]);
      acc[1][0] = MFMA16(a1, bb0, acc[1][0]); acc[1][1] = MFMA16(a1, bb1, acc[1][1]);
      acc[1][2] = MFMA16(a1, bb2, acc[1][2]); acc[1][3] = MFMA16(a1, bb3, acc[1][3]);
      acc[2][0] = MFMA16(a2, bb0, acc[2][0]); acc[2][1] = MFMA16(a2, bb1, acc[2][1]);
      acc[2][2] = MFMA16(a2, bb2, acc[2][2]); acc[2][3] = MFMA16(a2, bb3, acc[2][3]);
      acc[3][0] = MFMA16(a3, bb0, acc[3][0]); acc[3][1] = MFMA16(a3, bb1, acc[3][1]);
      acc[3][2] = MFMA16(a3, bb2, acc[3][2]); acc[3][3] = MFMA16(a3, bb3, acc[3][3]);
      __syncthreads();   // drains glld(kk+1) issued ~1 full iter ago
    }

    // stage GEMM2 chunk0 -> sB0 (latency overlapped by epilogue below)
    {
      const u16* src = Wgf + tid * 8;
      #pragma unroll
      for (int j = 0; j < 4; ++j) glld16(src + j * 4096, sB0 + tid * 8 + j * 4096);
    }
    // ---------- epilogue1: x2 = acc + b2; keep packed in regs; X2 -> sA ----------
    u32 x2p[4][4][2];   // packed bf16: [0]=r0|r1<<16, [1]=r2|r3<<16
    {
      float b2v[4];
      #pragma unroll
      for (int nt = 0; nt < 4; ++nt) b2v[nt] = b2[f * H + wid * 64 + nt * 16 + col];
      #pragma unroll
      for (int mt = 0; mt < 4; ++mt)
        #pragma unroll
        for (int nt = 0; nt < 4; ++nt) {
          const float x0 = acc[mt][nt][0] + b2v[nt];
          const float x1 = acc[mt][nt][1] + b2v[nt];
          const float x2 = acc[mt][nt][2] + b2v[nt];
          const float x3 = acc[mt][nt][3] + b2v[nt];
          const u32 o01 = (u32)f2bf(x0) | ((u32)f2bf(x1) << 16);
          const u32 o23 = (u32)f2bf(x2) | ((u32)f2bf(x3) << 16);
          x2p[mt][nt][0] = o01; x2p[mt][nt][1] = o23;
          // lane-pair exchange: even lane ends with (r0,r1) dwords for n-pair,
          // odd with (r2,r3). dword = val(n_even) | val(n_odd)<<16.
          const u32 send = even ? o23 : o01;
          const u32 recv = (u32)__shfl_xor((int)send, 1, 64);
          const u32 hi = even ? recv : o23;
          const u32 lo = even ? o01 : recv;
          const u32 dlo = __builtin_amdgcn_perm(hi, lo, 0x05040100u);  // rA pair
          const u32 dhi = __builtin_amdgcn_perm(hi, lo, 0x07060302u);  // rA+1 pair
          const int n  = wid * 64 + nt * 16 + col;
          const int np = n & ~1;
          const int mA = mt * 16 + quad * 4 + (even ? 0 : 2);
          const int iA = mA * 512 + ((((np >> 3) ^ (mA & 7)) << 3) + (np & 7));
          const int mB = mA + 1;
          const int iB = mB * 512 + ((((np >> 3) ^ (mB & 7)) << 3) + (np & 7));
          *(u32*)&sA[iA] = dlo;
          *(u32*)&sA[iB] = dhi;
        }
    }
    __syncthreads();   // drains glld G2-chunk0 + X2 writes

    // ================= GEMM2: Gpre = X2 @ Wgf =================
    #pragma unroll
    for (int mt = 0; mt < 4; ++mt)
      #pragma unroll
      for (int nt = 0; nt < 4; ++nt) acc[mt][nt] = (f32x4){0.f, 0.f, 0.f, 0.f};
    #pragma unroll 1
    for (int kk = 0; kk < 16; ++kk) {
      if (kk < 15) {
        const u16* src = Wgf + (kk + 1) * 16384 + tid * 8;
        u16* dst = (((kk + 1) & 1) ? sB1 : sB0) + tid * 8;
        #pragma unroll
        for (int j = 0; j < 4; ++j) glld16(src + j * 4096, dst + j * 4096);
      }
      const u16* bp = ((kk & 1) ? sB1 : sB0) + wid * 2048 + lane * 8;
      short8 bb0 = *(const short8*)(bp);
      short8 bb1 = *(const short8*)(bp + 512);
      short8 bb2 = *(const short8*)(bp + 1024);
      short8 bb3 = *(const short8*)(bp + 1536);
      const int g = (kk * 4 + quad) ^ (col & 7);
      short8 a0 = *(const short8*)&sA[(     col) * 512 + g * 8];
      short8 a1 = *(const short8*)&sA[(16 + col) * 512 + g * 8];
      short8 a2 = *(const short8*)&sA[(32 + col) * 512 + g * 8];
      short8 a3 = *(const short8*)&sA[(48 + col) * 512 + g * 8];
      acc[0][0] = MFMA16(a0, bb0, acc[0][0]); acc[0][1] = MFMA16(a0, bb1, acc[0][1]);
      acc[0][2] = MFMA16(a0, bb2, acc[0][2]); acc[0][3] = MFMA16(a0, bb3, acc[0][3]);
      acc[1][0] = MFMA16(a1, bb0, acc[1][0]); acc[1][1] = MFMA16(a1, bb1, acc[1][1]);
      acc[1][2] = MFMA16(a1, bb2, acc[1][2]); acc[1][3] = MFMA16(a1, bb3, acc[1][3]);
      acc[2][0] = MFMA16(a2, bb0, acc[2][0]); acc[2][1] = MFMA16(a2, bb1, acc[2][1]);
      acc[2][2] = MFMA16(a2, bb2, acc[2][2]); acc[2][3] = MFMA16(a2, bb3, acc[2][3]);
      acc[3][0] = MFMA16(a3, bb0, acc[3][0]); acc[3][1] = MFMA16(a3, bb1, acc[3][1]);
      acc[3][2] = MFMA16(a3, bb2, acc[3][2]); acc[3][3] = MFMA16(a3, bb3, acc[3][3]);
      __syncthreads();
    }

    // ---------- gate + LN + selection-weighted accumulate (x2 from regs) ----------
    {
      const float selw = sel_ws[bidx * NF + f];
      float bgv[4];
      #pragma unroll
      for (int nt = 0; nt < 4; ++nt) bgv[nt] = bg[f * H + wid * 64 + nt * 16 + col];
      float vr[4][4];
      #pragma unroll
      for (int mt = 0; mt < 4; ++mt)
        #pragma unroll
        for (int reg = 0; reg < 4; ++reg)
          vr[mt][reg] = in[(row0 + mt * 16 + quad * 4 + reg) * NF + f];

      float rs[4][4], rq[4][4];
      #pragma unroll
      for (int mt = 0; mt < 4; ++mt)
        #pragma unroll
        for (int reg = 0; reg < 4; ++reg) { rs[mt][reg] = 0.f; rq[mt][reg] = 0.f; }

      #pragma unroll
      for (int mt = 0; mt < 4; ++mt)
        #pragma unroll
        for (int reg = 0; reg < 4; ++reg)
          #pragma unroll
          for (int nt = 0; nt < 4; ++nt) {
            const u32 w = x2p[mt][nt][reg >> 1];
            const float x2v = bf2f((reg & 1) ? (w >> 16) : (w & 0xffffu));
            const float gv = sigmoid_f(acc[mt][nt][reg] + bgv[nt]);
            const float gt = gv * x2v + (1.0f - gv) * vr[mt][reg];
            acc[mt][nt][reg] = gt;
            rs[mt][reg] += gt; rq[mt][reg] += gt * gt;
          }
      #pragma unroll
      for (int msk = 8; msk >= 1; msk >>= 1)
        #pragma unroll
        for (int mt = 0; mt < 4; ++mt)
          #pragma unroll
          for (int reg = 0; reg < 4; ++reg) {
            rs[mt][reg] += __shfl_xor(rs[mt][reg], msk, 64);
            rq[mt][reg] += __shfl_xor(rq[mt][reg], msk, 64);
          }
      if (col == 0) {
        #pragma unroll
        for (int mt = 0; mt < 4; ++mt)
          #pragma unroll
          for (int reg = 0; reg < 4; ++reg) {
            const int m = mt * 16 + quad * 4 + reg;
            float2 sq; sq.x = rs[mt][reg]; sq.y = rq[mt][reg];
            *(float2*)&sRed[m * 16 + wid * 2] = sq;   // sA dead after GEMM2
          }
      }
      __syncthreads();

      float gmv[4], btv[4];
      #pragma unroll
      for (int nt = 0; nt < 4; ++nt) {
        const int n = wid * 64 + nt * 16 + col;
        gmv[nt] = gamma[f * H + n];
        btv[nt] = beta[f * H + n];
      }
      #pragma unroll
      for (int mt = 0; mt < 4; ++mt)
        #pragma unroll
        for (int reg = 0; reg < 4; ++reg) {
          const int m = mt * 16 + quad * 4 + reg;
          float s = 0.f, q = 0.f;
          #pragma unroll
          for (int w = 0; w < 8; ++w) {
            float2 sq = *(float2*)&sRed[m * 16 + w * 2];
            s += sq.x; q += sq.y;
          }
          const float mu   = s * (1.0f / H);
          const float rstd = rsqrtf(q * (1.0f / H) - mu * mu + 1e-3f);
          #pragma unroll
          for (int nt = 0; nt < 4; ++nt) {
            const float tv = gmv[nt] * ((acc[mt][nt][reg] - mu) * rstd) + btv[nt];
            outacc[mt][nt][reg] = fmaf(selw, tv, outacc[mt][nt][reg]);
          }
        }
      __syncthreads();   // sRed reads done before next f's A1 overwrites sA
    }
  }

  // ---------- store selected [MTOT, H] ----------
  #pragma unroll
  for (int mt = 0; mt < 4; ++mt)
    #pragma unroll
    for (int reg = 0; reg < 4; ++reg) {
      const int m = row0 + mt * 16 + quad * 4 + reg;
      #pragma unroll
      for (int nt = 0; nt < 4; ++nt) {
        const int n = wid * 64 + nt * 16 + col;
        out[(size_t)m * H + n] = outacc[mt][nt][reg];
      }
    }
}

extern "C" void kernel_launch(void* const* d_in, const int* in_sizes, int n_in,
                              void* d_out, int out_size, void* d_ws, size_t ws_size,
                              hipStream_t stream) {
  const float* in_     = (const float*)d_in[0];
  const float* W1c     = (const float*)d_in[1];
  const float* b1c     = (const float*)d_in[2];
  const float* W2c     = (const float*)d_in[3];
  const float* b2c     = (const float*)d_in[4];
  const float* Wgc     = (const float*)d_in[5];
  const float* bgc     = (const float*)d_in[6];
  const float* gamma_c = (const float*)d_in[7];
  const float* beta_c  = (const float*)d_in[8];
  const float* Wsel    = (const float*)d_in[9];
  const float* bsel    = (const float*)d_in[10];
  const float* w1      = (const float*)d_in[11];
  const float* b1v     = (const float*)d_in[12];
  const float* W2      = (const float*)d_in[13];
  const float* b2v     = (const float*)d_in[14];
  const float* Wg      = (const float*)d_in[15];
  const float* bgv     = (const float*)d_in[16];
  const float* gma     = (const float*)d_in[17];
  const float* bta     = (const float*)d_in[18];

  float* out_sel = (float*)d_out;                      // [MTOT, H]
  float* out_w   = (float*)d_out + (size_t)MTOT * H;   // [B, T, 1, F]

  float* sel_ws = (float*)d_ws;                        // 4 KB
  u16*   W2p    = (u16*)((char*)d_ws + 4096);          // 2 MB
  u16*   Wgp    = W2p + (size_t)NF * H * H;            // 2 MB

  hipLaunchKernelGGL(pack_weights, dim3(1024), dim3(256), 0, stream, W2, Wg, W2p, Wgp);
  hipLaunchKernelGGL(ctx_grn_kernel, dim3(256), dim3(512), 0, stream,
                     in_, W1c, b1c, W2c, b2c, Wgc, bgc, gamma_c, beta_c,
                     Wsel, bsel, sel_ws, out_w);
  hipLaunchKernelGGL(vsn_mfma, dim3(MTOT / 64), dim3(512), 0, stream,
                     in_, w1, b1v, b2v, bgv, gma, bta, W2p, Wgp, sel_ws, out_sel);
}

// Round 4
// 552.058 us; speedup vs baseline: 1.2488x; 1.2488x over previous
//
#include <hip/hip_runtime.h>
#include <math.h>

// VariableSelectionNetwork — round 3.
// Fixes vs round 2 (both measured at ~24% occupancy = 2 waves/SIMD, reg-bound):
//  * vsn_mfma: 1024-thr blocks, wave tile mt4 x nt2 -> ~120 regs -> 4 waves/SIMD.
//  * ctx GRN rewritten as MFMA (was ~130us latency-bound fp32 matvecs).
//  * fast elu/sigmoid via v_exp; rotated A1 stores (LDS write conflicts);
//    two-stage LN reduce with stride-36 partials.

#define H 512
#define NF 4
#define MTOT 32768

typedef unsigned short u16;
typedef unsigned int u32;
typedef __attribute__((ext_vector_type(8))) short short8;   // 8 bf16 = 4 VGPRs
typedef __attribute__((ext_vector_type(4))) float f32x4;    // MFMA C/D

__device__ __forceinline__ u16 f2bf(float x) {
  union { float f; u32 u; } v; v.f = x;
  return (u16)((v.u + 0x7fffu + ((v.u >> 16) & 1u)) >> 16);  // RNE
}
__device__ __forceinline__ float bf2f(u32 h16) {
  union { u32 u; float f; } v; v.u = h16 << 16;
  return v.f;
}
__device__ __forceinline__ float elu_f(float x) {
  return x > 0.0f ? x : (__expf(x) - 1.0f);
}
__device__ __forceinline__ float sigmoid_f(float x) {
  return __builtin_amdgcn_rcpf(1.0f + __expf(-x));
}

// async global->LDS, 16B per lane; LDS dest = wave-uniform base + lane*16.
__device__ __forceinline__ void glld16(const void* g, void* l) {
  __builtin_amdgcn_global_load_lds(
      (const __attribute__((address_space(1))) u32*)(unsigned long long)(uintptr_t)g,
      (__attribute__((address_space(3))) u32*)(u32)(uintptr_t)l, 16, 0, 0);
}

#define MFMA16(a, b, c) __builtin_amdgcn_mfma_f32_16x16x32_bf16((a), (b), (c), 0, 0, 0)

// ---------------- pack_weights: fp32 -> bf16 B-fragment-major ----------------
// Packed per matrix: (((kk*32 + ntg)*64 + lane)*8 + j); chunk kk = 32k x 512n
// = 32KB contiguous. mats 0-3 W2[f], 4-7 Wg[f], 8 W1c, 9 W2c, 10 Wgc.
__global__ __launch_bounds__(256)
void pack_weights(const float* __restrict__ W2, const float* __restrict__ Wg,
                  const float* __restrict__ W1c, const float* __restrict__ W2c,
                  const float* __restrict__ Wgc,
                  u16* __restrict__ W2p, u16* __restrict__ Wgp, u16* __restrict__ Cp) {
  int g = blockIdx.x * 256 + threadIdx.x;       // 0 .. 11*32768-1
  int r = g & 32767; int mat = g >> 15;
  if (mat >= 11) return;
  int lane = r & 63, nt = (r >> 6) & 31, kk = (r >> 11) & 15;
  const float* src; u16* dst;
  if (mat < 4)      { src = W2 + (size_t)mat * 262144;       dst = W2p + (size_t)mat * 262144; }
  else if (mat < 8) { src = Wg + (size_t)(mat - 4) * 262144; dst = Wgp + (size_t)(mat - 4) * 262144; }
  else              { src = (mat == 8 ? W1c : (mat == 9 ? W2c : Wgc));
                      dst = Cp + (size_t)(mat - 8) * 262144; }
  dst += (((size_t)kk * 32 + nt) * 64 + lane) * 8;
  int n  = nt * 16 + (lane & 15);
  int k0 = kk * 32 + (lane >> 4) * 8;
  short8 pk;
  #pragma unroll
  for (int j = 0; j < 8; ++j) pk[j] = (short)f2bf(src[(size_t)(k0 + j) * H + n]);
  *(short8*)dst = pk;
}

// ======================= shared GEMM-tile machinery =======================
// Block: 1024 thr = 16 waves. M-tile 64 rows. Wave wid owns cols wid*32..+31
// (nt=2 of 16). Per-thread frags: mt=4, nt=2. sA: 64KB bf16 [m][k] XOR-swizzled
// (16B groups, grp = (k>>3) ^ (m&7)). sB: 2 x 32KB chunk buffers (BK=32).

struct TileCtx {
  int tid, wid, lane, quad, col;
};

// one GEMM K-loop: C = sA @ Wp(chunks), double-buffered glld staging.
// Caller must have chunk0 already staged into sB0 and synced.
template <bool PREFETCH_TAIL>
__device__ __forceinline__ void gemm_kloop(const TileCtx& c, const u16* Wp,
                                           const u16* nextWp,  // chunk0 of next GEMM (if PREFETCH_TAIL)
                                           u16* sA, u16* sB0, u16* sB1,
                                           f32x4 acc[4][2]) {
  #pragma unroll 1
  for (int kk = 0; kk < 16; ++kk) {
    if (kk < 15) {
      const u16* src = Wp + (kk + 1) * 16384 + c.tid * 8;
      u16* dst = (((kk + 1) & 1) ? sB1 : sB0) + c.tid * 8;
      glld16(src, dst);
      glld16(src + 8192, dst + 8192);
    } else if (PREFETCH_TAIL) {
      // stage next GEMM's chunk0 into sB0 (kk=15 reads sB1)
      const u16* src = nextWp + c.tid * 8;
      glld16(src, sB0 + c.tid * 8);
      glld16(src + 8192, sB0 + c.tid * 8 + 8192);
    }
    const u16* bp = ((kk & 1) ? sB1 : sB0) + c.wid * 1024 + c.lane * 8;
    short8 bb0 = *(const short8*)(bp);
    short8 bb1 = *(const short8*)(bp + 512);
    const int kq = kk * 4 + c.quad;
    const int s0 = (kq ^ (c.col & 7)) * 8;
    short8 a0 = *(const short8*)&sA[(     c.col) * 512 + s0];
    short8 a1 = *(const short8*)&sA[(16 + c.col) * 512 + s0];
    short8 a2 = *(const short8*)&sA[(32 + c.col) * 512 + s0];
    short8 a3 = *(const short8*)&sA[(48 + c.col) * 512 + s0];
    acc[0][0] = MFMA16(a0, bb0, acc[0][0]); acc[0][1] = MFMA16(a0, bb1, acc[0][1]);
    acc[1][0] = MFMA16(a1, bb0, acc[1][0]); acc[1][1] = MFMA16(a1, bb1, acc[1][1]);
    acc[2][0] = MFMA16(a2, bb0, acc[2][0]); acc[2][1] = MFMA16(a2, bb1, acc[2][1]);
    acc[3][0] = MFMA16(a3, bb0, acc[3][0]); acc[3][1] = MFMA16(a3, bb1, acc[3][1]);
    __syncthreads();
  }
}

// store one C-layout value-pair set into sA[m][k] bf16 via lane-pair exchange:
// even lane ends holding rows (r0,r1)'s dword for an n-pair, odd rows (r2,r3).
__device__ __forceinline__ void store_x2_pair(const TileCtx& c, u16* sA,
                                              int mt, int nt, u32 o01, u32 o23) {
  const bool even = (c.lane & 1) == 0;
  const u32 send = even ? o23 : o01;
  const u32 recv = (u32)__shfl_xor((int)send, 1, 64);
  const u32 hi = even ? recv : o23;
  const u32 lo = even ? o01 : recv;
  const u32 dlo = __builtin_amdgcn_perm(hi, lo, 0x05040100u);
  const u32 dhi = __builtin_amdgcn_perm(hi, lo, 0x07060302u);
  const int n  = c.wid * 32 + nt * 16 + c.col;
  const int np = n & ~1;
  const int mA = mt * 16 + c.quad * 4 + (even ? 0 : 2);
  const int iA = mA * 512 + ((((np >> 3) ^ (mA & 7)) << 3) + (np & 7));
  const int mB = mA + 1;
  const int iB = mB * 512 + ((((np >> 3) ^ (mB & 7)) << 3) + (np & 7));
  *(u32*)&sA[iA] = dlo;
  *(u32*)&sA[iB] = dhi;
}

// LN over 512 cols for 64 rows. gt values in acc (C-layout). Returns mu/rstd
// per (mt,reg) via sMR. sRedF = fp32 overlay (stride-36 partials + final).
__device__ __forceinline__ void ln_reduce(const TileCtx& c, float* sRedF,
                                          f32x4 acc[4][2]) {
  #pragma unroll
  for (int mt = 0; mt < 4; ++mt) {
    float rs[4] = {0.f, 0.f, 0.f, 0.f}, rq[4] = {0.f, 0.f, 0.f, 0.f};
    #pragma unroll
    for (int reg = 0; reg < 4; ++reg)
      #pragma unroll
      for (int nt = 0; nt < 2; ++nt) {
        const float gt = acc[mt][nt][reg];
        rs[reg] += gt; rq[reg] += gt * gt;
      }
    #pragma unroll
    for (int msk = 8; msk >= 1; msk >>= 1)
      #pragma unroll
      for (int reg = 0; reg < 4; ++reg) {
        rs[reg] += __shfl_xor(rs[reg], msk, 64);
        rq[reg] += __shfl_xor(rq[reg], msk, 64);
      }
    if (c.col == 0) {
      #pragma unroll
      for (int reg = 0; reg < 4; ++reg) {
        const int m = mt * 16 + c.quad * 4 + reg;
        float2 sq; sq.x = rs[reg]; sq.y = rq[reg];
        *(float2*)&sRedF[m * 36 + c.wid * 2] = sq;
      }
    }
  }
  __syncthreads();
  if (c.tid < 64) {
    const int row = c.tid;
    float s = 0.f, q = 0.f;
    #pragma unroll
    for (int jj = 0; jj < 8; ++jj) {
      float4 v = *(float4*)&sRedF[row * 36 + jj * 4];
      s += v.x + v.z; q += v.y + v.w;
    }
    const float mu = s * (1.0f / H);
    const float rstd = rsqrtf(q * (1.0f / H) - mu * mu + 1e-3f);
    float2 mr; mr.x = mu; mr.y = rstd;
    *(float2*)&sRedF[2304 + row * 2] = mr;
  }
  __syncthreads();
}

// ---------------- ctx GRN as MFMA: 4 blocks x 64 batch rows ----------------
__global__ __launch_bounds__(1024)
void ctx_mfma(const float* __restrict__ in,       // [B, 512] flat
              const u16* __restrict__ Cp,         // W1cp | W2cp | Wgcp
              const float* __restrict__ b1c, const float* __restrict__ b2c,
              const float* __restrict__ bgc,
              const float* __restrict__ gamma_c, const float* __restrict__ beta_c,
              const float* __restrict__ Wsel, const float* __restrict__ bsel,
              float* __restrict__ sel_ws,         // [B, F]
              float* __restrict__ selw_out)       // [B, T, 1, F]
{
  __shared__ __align__(16) u16 smem[65536];
  u16* const sA  = smem;
  u16* const sB0 = smem + 32768;
  u16* const sB1 = smem + 49152;
  float* const sRedF = (float*)smem;
  float* const sZ   = (float*)sB0;        // [64][4] logits
  float* const sSel = (float*)sB0 + 256;  // [64][4] softmax

  TileCtx c;
  c.tid = threadIdx.x; c.wid = c.tid >> 6; c.lane = c.tid & 63;
  c.quad = c.lane >> 4; c.col = c.lane & 15;
  const int b0 = blockIdx.x * 64;
  const u16* W1cp = Cp;
  const u16* W2cp = Cp + 262144;
  const u16* Wgcp = Cp + 524288;

  // stage W1c chunk0
  glld16(W1cp + c.tid * 8, sB0 + c.tid * 8);
  glld16(W1cp + c.tid * 8 + 8192, sB0 + c.tid * 8 + 8192);

  // A0: flat -> sA bf16 (rotated k-group order to spread LDS write banks)
  {
    const int m = c.tid >> 4;
    const int kb = (c.tid & 15) * 32;
    const float* rowp = in + (size_t)(b0 + m) * H;
    #pragma unroll
    for (int gg = 0; gg < 4; ++gg) {
      const int ge = (gg + (c.tid & 15)) & 3;
      const int k = kb + ge * 8;
      float4 v0 = *(const float4*)&rowp[k];
      float4 v1 = *(const float4*)&rowp[k + 4];
      short8 pk;
      pk[0] = (short)f2bf(v0.x); pk[1] = (short)f2bf(v0.y);
      pk[2] = (short)f2bf(v0.z); pk[3] = (short)f2bf(v0.w);
      pk[4] = (short)f2bf(v1.x); pk[5] = (short)f2bf(v1.y);
      pk[6] = (short)f2bf(v1.z); pk[7] = (short)f2bf(v1.w);
      const int grp = (k >> 3) ^ (m & 7);
      *(short8*)&sA[m * 512 + grp * 8] = pk;
    }
  }
  __syncthreads();

  f32x4 acc[4][2];
  #pragma unroll
  for (int mt = 0; mt < 4; ++mt) { acc[mt][0] = (f32x4){0,0,0,0}; acc[mt][1] = (f32x4){0,0,0,0}; }

  // GEMM1: x1 = elu(flat@W1c + b1c) -> sA
  gemm_kloop<true>(c, W1cp, W2cp, sA, sB0, sB1, acc);
  {
    float bv[2] = { b1c[c.wid * 32 + c.col], b1c[c.wid * 32 + 16 + c.col] };
    #pragma unroll
    for (int mt = 0; mt < 4; ++mt)
      #pragma unroll
      for (int nt = 0; nt < 2; ++nt) {
        const float x0 = elu_f(acc[mt][nt][0] + bv[nt]);
        const float x1 = elu_f(acc[mt][nt][1] + bv[nt]);
        const float x2 = elu_f(acc[mt][nt][2] + bv[nt]);
        const float x3 = elu_f(acc[mt][nt][3] + bv[nt]);
        store_x2_pair(c, sA, mt, nt,
                      (u32)f2bf(x0) | ((u32)f2bf(x1) << 16),
                      (u32)f2bf(x2) | ((u32)f2bf(x3) << 16));
      }
  }
  __syncthreads();

  // GEMM2: x = x1@W2c + b2c (keep fp32 in regs, also -> sA)
  float xr[4][2][4];
  #pragma unroll
  for (int mt = 0; mt < 4; ++mt) { acc[mt][0] = (f32x4){0,0,0,0}; acc[mt][1] = (f32x4){0,0,0,0}; }
  gemm_kloop<true>(c, W2cp, Wgcp, sA, sB0, sB1, acc);
  {
    float bv[2] = { b2c[c.wid * 32 + c.col], b2c[c.wid * 32 + 16 + c.col] };
    #pragma unroll
    for (int mt = 0; mt < 4; ++mt)
      #pragma unroll
      for (int nt = 0; nt < 2; ++nt) {
        #pragma unroll
        for (int reg = 0; reg < 4; ++reg) xr[mt][nt][reg] = acc[mt][nt][reg] + bv[nt];
        store_x2_pair(c, sA, mt, nt,
                      (u32)f2bf(xr[mt][nt][0]) | ((u32)f2bf(xr[mt][nt][1]) << 16),
                      (u32)f2bf(xr[mt][nt][2]) | ((u32)f2bf(xr[mt][nt][3]) << 16));
      }
  }
  __syncthreads();

  // GEMM3: gpre = x@Wgc; gate + skip + LN -> ctx
  #pragma unroll
  for (int mt = 0; mt < 4; ++mt) { acc[mt][0] = (f32x4){0,0,0,0}; acc[mt][1] = (f32x4){0,0,0,0}; }
  gemm_kloop<false>(c, Wgcp, nullptr, sA, sB0, sB1, acc);
  {
    float bv[2] = { bgc[c.wid * 32 + c.col], bgc[c.wid * 32 + 16 + c.col] };
    #pragma unroll
    for (int mt = 0; mt < 4; ++mt)
      #pragma unroll
      for (int nt = 0; nt < 2; ++nt) {
        const int n = c.wid * 32 + nt * 16 + c.col;
        #pragma unroll
        for (int reg = 0; reg < 4; ++reg) {
          const int m = mt * 16 + c.quad * 4 + reg;
          const float fl = in[(size_t)(b0 + m) * H + n];
          const float gv = sigmoid_f(acc[mt][nt][reg] + bv[nt]);
          acc[mt][nt][reg] = gv * xr[mt][nt][reg] + (1.0f - gv) * fl;
        }
      }
  }
  ln_reduce(c, sRedF, acc);   // overlays sA; sA re-written below after LN
  // ctx -> sA (plain [m][n] bf16 layout) for the sel dot
  {
    float gm[2], bt[2];
    #pragma unroll
    for (int nt = 0; nt < 2; ++nt) {
      const int n = c.wid * 32 + nt * 16 + c.col;
      gm[nt] = gamma_c[n]; bt[nt] = beta_c[n];
    }
    u16 cv[4][2][4];
    #pragma unroll
    for (int mt = 0; mt < 4; ++mt)
      #pragma unroll
      for (int reg = 0; reg < 4; ++reg) {
        const int m = mt * 16 + c.quad * 4 + reg;
        float2 mr = *(float2*)&sRedF[2304 + m * 2];
        #pragma unroll
        for (int nt = 0; nt < 2; ++nt)
          cv[mt][nt][reg] = f2bf(gm[nt] * ((acc[mt][nt][reg] - mr.x) * mr.y) + bt[nt]);
      }
    __syncthreads();   // sRedF reads done; sA region reusable
    #pragma unroll
    for (int mt = 0; mt < 4; ++mt)
      #pragma unroll
      for (int reg = 0; reg < 4; ++reg) {
        const int m = mt * 16 + c.quad * 4 + reg;
        #pragma unroll
        for (int nt = 0; nt < 2; ++nt)
          sA[m * 512 + c.wid * 32 + nt * 16 + c.col] = cv[mt][nt][reg];
      }
  }
  __syncthreads();

  // sel logits: 256 threads, (row, f)
  if (c.tid < 256) {
    const int r = c.tid >> 2, f = c.tid & 3;
    float z = bsel[f];
    const u16* rowp = &sA[r * 512];
    #pragma unroll 8
    for (int h = 0; h < H; ++h) z += bf2f(rowp[h]) * Wsel[h * NF + f];
    sZ[r * 4 + f] = z;
  }
  __syncthreads();
  if (c.tid < 64) {
    const int r = c.tid;
    float z0 = sZ[r*4], z1 = sZ[r*4+1], z2 = sZ[r*4+2], z3 = sZ[r*4+3];
    float mx = fmaxf(fmaxf(z0, z1), fmaxf(z2, z3));
    float e0 = __expf(z0-mx), e1 = __expf(z1-mx), e2 = __expf(z2-mx), e3 = __expf(z3-mx);
    float inv = __builtin_amdgcn_rcpf(e0 + e1 + e2 + e3);
    sSel[r*4]   = e0*inv; sSel[r*4+1] = e1*inv;
    sSel[r*4+2] = e2*inv; sSel[r*4+3] = e3*inv;
  }
  __syncthreads();
  if (c.tid < 256) {
    const int r = c.tid >> 2, f = c.tid & 3;
    sel_ws[(b0 + r) * NF + f] = sSel[r * 4 + f];
  }
  {
    const int m = c.tid >> 4;
    const int jb = (c.tid & 15) * 32;
    float s0 = sSel[m*4], s1 = sSel[m*4+1], s2 = sSel[m*4+2], s3 = sSel[m*4+3];
    float4 v; v.x = s0; v.y = s1; v.z = s2; v.w = s3;
    #pragma unroll
    for (int j = 0; j < 8; ++j)
      *(float4*)&selw_out[(size_t)(b0 + m) * H + jb + j * 4] = v;
  }
}

// ---------------- vsn_mfma: per-variable GRNs + weighted selection ----------------
__global__ __launch_bounds__(1024)
void vsn_mfma(const float* __restrict__ in,     // [MTOT, F]
              const float* __restrict__ w1, const float* __restrict__ b1,
              const float* __restrict__ b2, const float* __restrict__ bg,
              const float* __restrict__ gamma, const float* __restrict__ beta,
              const u16* __restrict__ W2p, const u16* __restrict__ Wgp,
              const float* __restrict__ sel_ws,  // [B, F]
              float* __restrict__ out)           // [MTOT, H]
{
  __shared__ __align__(16) u16 smem[65536];
  u16* const sA  = smem;
  u16* const sB0 = smem + 32768;
  u16* const sB1 = smem + 49152;
  float* const sRedF = (float*)smem;

  TileCtx c;
  c.tid = threadIdx.x; c.wid = c.tid >> 6; c.lane = c.tid & 63;
  c.quad = c.lane >> 4; c.col = c.lane & 15;
  const int row0 = blockIdx.x * 64;
  const int bidx = row0 >> 7;

  f32x4 outacc[4][2];
  #pragma unroll
  for (int mt = 0; mt < 4; ++mt) { outacc[mt][0] = (f32x4){0,0,0,0}; outacc[mt][1] = (f32x4){0,0,0,0}; }

  for (int f = 0; f < NF; ++f) {
    const u16* W2f = W2p + (size_t)f * 262144;
    const u16* Wgf = Wgp + (size_t)f * 262144;

    // stage GEMM1 chunk0 (overlapped by A1 phase)
    glld16(W2f + c.tid * 8, sB0 + c.tid * 8);
    glld16(W2f + c.tid * 8 + 8192, sB0 + c.tid * 8 + 8192);

    // A1: sA[m][k] = bf16(elu(v[m]*w1[k] + b1[k])), rotated k-group order
    {
      const int m  = c.tid >> 4;
      const int kb = (c.tid & 15) * 32;
      const float v = in[(size_t)(row0 + m) * NF + f];
      const float* w1f = w1 + f * H;
      const float* b1f = b1 + f * H;
      #pragma unroll
      for (int gg = 0; gg < 4; ++gg) {
        const int ge = (gg + (c.tid & 15)) & 3;
        const int k = kb + ge * 8;
        short8 pk;
        #pragma unroll
        for (int j = 0; j < 8; ++j)
          pk[j] = (short)f2bf(elu_f(fmaf(v, w1f[k + j], b1f[k + j])));
        const int grp = (k >> 3) ^ (m & 7);
        *(short8*)&sA[m * 512 + grp * 8] = pk;
      }
    }
    __syncthreads();

    f32x4 acc[4][2];
    #pragma unroll
    for (int mt = 0; mt < 4; ++mt) { acc[mt][0] = (f32x4){0,0,0,0}; acc[mt][1] = (f32x4){0,0,0,0}; }

    // GEMM1 (tail-prefetches Wgf chunk0 into sB0)
    gemm_kloop<true>(c, W2f, Wgf, sA, sB0, sB1, acc);

    // epilogue1: x2 = acc + b2 -> packed regs + sA
    u32 x2p[4][2][2];
    {
      float bv[2] = { b2[f * H + c.wid * 32 + c.col], b2[f * H + c.wid * 32 + 16 + c.col] };
      #pragma unroll
      for (int mt = 0; mt < 4; ++mt)
        #pragma unroll
        for (int nt = 0; nt < 2; ++nt) {
          const float x0 = acc[mt][nt][0] + bv[nt];
          const float x1 = acc[mt][nt][1] + bv[nt];
          const float x2 = acc[mt][nt][2] + bv[nt];
          const float x3 = acc[mt][nt][3] + bv[nt];
          const u32 o01 = (u32)f2bf(x0) | ((u32)f2bf(x1) << 16);
          const u32 o23 = (u32)f2bf(x2) | ((u32)f2bf(x3) << 16);
          x2p[mt][nt][0] = o01; x2p[mt][nt][1] = o23;
          store_x2_pair(c, sA, mt, nt, o01, o23);
        }
    }
    __syncthreads();

    // GEMM2
    #pragma unroll
    for (int mt = 0; mt < 4; ++mt) { acc[mt][0] = (f32x4){0,0,0,0}; acc[mt][1] = (f32x4){0,0,0,0}; }
    gemm_kloop<false>(c, Wgf, nullptr, sA, sB0, sB1, acc);

    // gate + LN + weighted accumulate
    {
      const float selw = sel_ws[bidx * NF + f];
      float bv[2] = { bg[f * H + c.wid * 32 + c.col], bg[f * H + c.wid * 32 + 16 + c.col] };
      #pragma unroll
      for (int mt = 0; mt < 4; ++mt) {
        float vr[4];
        #pragma unroll
        for (int reg = 0; reg < 4; ++reg)
          vr[reg] = in[(size_t)(row0 + mt * 16 + c.quad * 4 + reg) * NF + f];
        #pragma unroll
        for (int nt = 0; nt < 2; ++nt)
          #pragma unroll
          for (int reg = 0; reg < 4; ++reg) {
            const u32 w = x2p[mt][nt][reg >> 1];
            const float x2v = bf2f((reg & 1) ? (w >> 16) : (w & 0xffffu));
            const float gv = sigmoid_f(acc[mt][nt][reg] + bv[nt]);
            acc[mt][nt][reg] = gv * x2v + (1.0f - gv) * vr[reg];
          }
      }
      ln_reduce(c, sRedF, acc);
      float gm[2], bt[2];
      #pragma unroll
      for (int nt = 0; nt < 2; ++nt) {
        const int n = f * H + c.wid * 32 + nt * 16 + c.col;
        gm[nt] = gamma[n]; bt[nt] = beta[n];
      }
      #pragma unroll
      for (int mt = 0; mt < 4; ++mt)
        #pragma unroll
        for (int reg = 0; reg < 4; ++reg) {
          const int m = mt * 16 + c.quad * 4 + reg;
          float2 mr = *(float2*)&sRedF[2304 + m * 2];
          #pragma unroll
          for (int nt = 0; nt < 2; ++nt) {
            const float tv = gm[nt] * ((acc[mt][nt][reg] - mr.x) * mr.y) + bt[nt];
            outacc[mt][nt][reg] = fmaf(selw, tv, outacc[mt][nt][reg]);
          }
        }
      __syncthreads();   // sRedF reads done before next f's A1 overwrites sA
    }
  }

  // store selected [MTOT, H]
  #pragma unroll
  for (int mt = 0; mt < 4; ++mt)
    #pragma unroll
    for (int reg = 0; reg < 4; ++reg) {
      const int m = row0 + mt * 16 + c.quad * 4 + reg;
      #pragma unroll
      for (int nt = 0; nt < 2; ++nt)
        out[(size_t)m * H + c.wid * 32 + nt * 16 + c.col] = outacc[mt][nt][reg];
    }
}

extern "C" void kernel_launch(void* const* d_in, const int* in_sizes, int n_in,
                              void* d_out, int out_size, void* d_ws, size_t ws_size,
                              hipStream_t stream) {
  const float* in_     = (const float*)d_in[0];
  const float* W1c     = (const float*)d_in[1];
  const float* b1c     = (const float*)d_in[2];
  const float* W2c     = (const float*)d_in[3];
  const float* b2c     = (const float*)d_in[4];
  const float* Wgc     = (const float*)d_in[5];
  const float* bgc     = (const float*)d_in[6];
  const float* gamma_c = (const float*)d_in[7];
  const float* beta_c  = (const float*)d_in[8];
  const float* Wsel    = (const float*)d_in[9];
  const float* bsel    = (const float*)d_in[10];
  const float* w1      = (const float*)d_in[11];
  const float* b1v     = (const float*)d_in[12];
  const float* W2      = (const float*)d_in[13];
  const float* b2v     = (const float*)d_in[14];
  const float* Wg      = (const float*)d_in[15];
  const float* bgv     = (const float*)d_in[16];
  const float* gma     = (const float*)d_in[17];
  const float* bta     = (const float*)d_in[18];

  float* out_sel = (float*)d_out;                      // [MTOT, H]
  float* out_w   = (float*)d_out + (size_t)MTOT * H;   // [B, T, 1, F]

  float* sel_ws = (float*)d_ws;                        // 4 KB
  u16*   W2p    = (u16*)((char*)d_ws + 4096);          // 2 MB
  u16*   Wgp    = W2p + (size_t)NF * H * H;            // 2 MB
  u16*   Cp     = Wgp + (size_t)NF * H * H;            // 1.5 MB (W1c|W2c|Wgc)

  hipLaunchKernelGGL(pack_weights, dim3(1408), dim3(256), 0, stream,
                     W2, Wg, W1c, W2c, Wgc, W2p, Wgp, Cp);
  hipLaunchKernelGGL(ctx_mfma, dim3(4), dim3(1024), 0, stream,
                     in_, Cp, b1c, b2c, bgc, gamma_c, beta_c,
                     Wsel, bsel, sel_ws, out_w);
  hipLaunchKernelGGL(vsn_mfma, dim3(MTOT / 64), dim3(1024), 0, stream,
                     in_, w1, b1v, b2v, bgv, gma, bta, W2p, Wgp, sel_ws, out_sel);
}